// Round 6
// baseline (314.177 us; speedup 1.0000x reference)
//
#include <hip/hip_runtime.h>

#define NN 50000
#define E_EDGES 800000
#define F_INN 128
#define HIDD 128
#define HEADS 8
#define CDIM 16
#define NCLS 10
#define NGG 64
#define NCONV 3
#define EPSS 1e-5f
#define NEG_SLOPE 0.2f

// Wt layout: per layer 144 rows (output cols) x 128 k, bf16.
#define WROWS 144
#define WSTRIDE (WROWS * 128)
#define BSTRIDE 144

// bucket partition: 128 dst nodes per bucket
#define BSH 7
#define BSZ 128
#define NB ((NN + BSZ - 1) / BSZ)   // 391
#define BIN_BLOCKS 256
#define BIN_CHUNK (E_EDGES / BIN_BLOCKS)   // 3125 exact
#define TABW 392                     // 391 offsets + sentinel
#define CAPB 4608                    // fixed csr region/bucket
#define SORT_BUF 4608
#define PW_KCH 32
#define GTILES ((NN + 127) / 128)    // 391 gemm blocks (128 rows each)
#define TPITCH 132                   // fp8 LDS tile row pitch (pad 4)

typedef __attribute__((ext_vector_type(8))) short short8;
typedef __attribute__((ext_vector_type(4))) float f32x4;
typedef __attribute__((ext_vector_type(2))) float f32x2;

__device__ __forceinline__ float lrelu(float x) { return x > 0.f ? x : NEG_SLOPE * x; }

__device__ __forceinline__ float bf2f(ushort u) {
    union { unsigned int i; float f; } v;
    v.i = ((unsigned int)u) << 16;
    return v.f;
}
__device__ __forceinline__ ushort f2bf(float f) {
    union { float f; unsigned int i; } v;
    v.f = f;
    unsigned int r = (v.i + 0x7fffu + ((v.i >> 16) & 1u)) >> 16;  // RNE
    return (ushort)r;
}
// OCP e4m3 encode via HW pack (saturating); take byte 0
__device__ __forceinline__ unsigned char f2fp8(float f) {
    int r = __builtin_amdgcn_cvt_pk_fp8_f32(f, f, 0, false);
    return (unsigned char)(r & 0xff);
}

// ================================================================ GEMM core (bf16-out path, layer 0 only)
__device__ __forceinline__ void gemm_core_l0(int tile, int t,
    const float* __restrict__ Ain, const ushort* __restrict__ Wt,
    const float* __restrict__ bias, ushort* __restrict__ Out, int n)
{
    int wave = t >> 6, lane = t & 63;
    int m16 = lane & 15, quad = lane >> 4;
    int rbase = tile * 128 + wave * 32;

    short8 afrag[2][4];
    #pragma unroll
    for (int tt = 0; tt < 2; ++tt) {
        int arow_i = rbase + tt * 16 + m16;
        size_t arow = (size_t)(arow_i < n ? arow_i : 0) * HIDD + quad * 8;
        const float* ap = Ain + arow;
        #pragma unroll
        for (int kk = 0; kk < 4; ++kk) {
            float4 lo = *(const float4*)(ap + kk * 32);
            float4 hi = *(const float4*)(ap + kk * 32 + 4);
            short8 f;
            f[0] = (short)f2bf(lo.x); f[1] = (short)f2bf(lo.y);
            f[2] = (short)f2bf(lo.z); f[3] = (short)f2bf(lo.w);
            f[4] = (short)f2bf(hi.x); f[5] = (short)f2bf(hi.y);
            f[6] = (short)f2bf(hi.z); f[7] = (short)f2bf(hi.w);
            afrag[tt][kk] = f;
        }
    }

    f32x4 acc[2][8];
    #pragma unroll
    for (int tt = 0; tt < 2; ++tt)
        #pragma unroll
        for (int nt = 0; nt < 8; ++nt) acc[tt][nt] = (f32x4){0.f, 0.f, 0.f, 0.f};

    #pragma unroll
    for (int nt = 0; nt < 8; ++nt) {
        const ushort* brow = Wt + (size_t)(nt * 16 + m16) * HIDD + quad * 8;
        #pragma unroll
        for (int kk = 0; kk < 4; ++kk) {
            short8 bfrag = *(const short8*)(brow + kk * 32);
            acc[0][nt] = __builtin_amdgcn_mfma_f32_16x16x32_bf16(afrag[0][kk], bfrag, acc[0][nt], 0, 0, 0);
            acc[1][nt] = __builtin_amdgcn_mfma_f32_16x16x32_bf16(afrag[1][kk], bfrag, acc[1][nt], 0, 0, 0);
        }
    }

    #pragma unroll
    for (int tt = 0; tt < 2; ++tt) {
        int tb = rbase + tt * 16;
        #pragma unroll
        for (int nt = 0; nt < 8; ++nt) {
            int col = nt * 16 + m16;
            float bv = bias[col];
            #pragma unroll
            for (int r = 0; r < 4; ++r) {
                int orow = tb + quad * 4 + r;
                if (orow < n) {
                    float v = fmaxf(acc[tt][nt][r] + bv, 0.f);
                    Out[(size_t)orow * HIDD + col] = f2bf(v);
                }
            }
        }
    }
}

// ================================================================ kernel A: prep + bin (R14-proven)
// R16: tab transposed to [bucket][chunk] so sort blocks read it coalesced.
__global__ __launch_bounds__(256) void prep_bin(
    const float* __restrict__ bn_feat, const float* __restrict__ w_feat,
    const float* __restrict__ b_feat, const float* __restrict__ bns_conv,
    const float* __restrict__ gat_w, const float* __restrict__ att_src,
    const float* __restrict__ att_dst, const int* __restrict__ src,
    const int* __restrict__ dst, ushort* __restrict__ Wt,
    float* __restrict__ bp, unsigned int* __restrict__ tmp, int* __restrict__ tab)
{
    __shared__ __align__(16) char smem[18560];
    int blk = blockIdx.x;
    int t = threadIdx.x;

    if (blk < 16) {
        float* Wl = (float*)smem;            // 32*129 floats
        float* aak = Wl + PW_KCH * 129;
        int layer = blk >> 2;
        int k0 = (blk & 3) * PW_KCH;
        const float* bn; const float* W;
        if (layer == 0) { bn = bn_feat; W = w_feat; }
        else { bn = bns_conv + (layer - 1) * 4 * HIDD; W = gat_w + (size_t)(layer - 1) * HIDD * HIDD; }
        if (t < PW_KCH) {
            int k = k0 + t;
            aak[t] = bn[k] * rsqrtf(bn[3 * HIDD + k] + EPSS);
        }
        for (int i = t; i < PW_KCH * 128; i += 256) {
            int kk = i >> 7, n = i & 127;
            Wl[kk * 129 + n] = W[(size_t)(k0 + kk) * 128 + n];
        }
        __syncthreads();
        ushort* wrow = Wt + (size_t)layer * WSTRIDE;
        for (int i = t; i < 128 * PW_KCH; i += 256) {
            int n = i >> 5, kk = i & 31;
            wrow[n * 128 + k0 + kk] = f2bf(aak[kk] * Wl[kk * 129 + n]);
        }
    } else if (blk < 20) {
        float* ccs = (float*)smem;
        int layer = blk - 16;
        const float* bn; const float* W;
        if (layer == 0) { bn = bn_feat; W = w_feat; }
        else { bn = bns_conv + (layer - 1) * 4 * HIDD; W = gat_w + (size_t)(layer - 1) * HIDD * HIDD; }
        if (t < 128) {
            float a = bn[t] * rsqrtf(bn[3 * HIDD + t] + EPSS);
            ccs[t] = bn[HIDD + t] - bn[2 * HIDD + t] * a;
        }
        __syncthreads();
        if (t < 128) {
            float bacc = (layer == 0) ? b_feat[t] : 0.f;
            for (int k = 0; k < 128; ++k) bacc += ccs[k] * W[(size_t)k * 128 + t];
            bp[layer * BSTRIDE + t] = bacc;
        }
    } else if (blk < 23) {
        float* Wl   = (float*)smem;               // 32*129 floats (16512 B)
        float* redS = (float*)(smem + 16512);     // 256 floats
        float* redD = redS + 256;
        int li = blk - 20;
        int L = li + 1;
        const float* bn = bns_conv + li * 4 * HIDD;
        const float* W  = gat_w + (size_t)li * HIDD * HIDD;
        const float* as = att_src + li * HEADS * CDIM;
        const float* ad = att_dst + li * HEADS * CDIM;
        ushort* Wo = Wt + (size_t)L * WSTRIDE;
        int kl = t >> 3, h = t & 7;
        float acc_s = 0.f, acc_d = 0.f;
        for (int c0 = 0; c0 < 4; ++c0) {
            int k0 = c0 * 32;
            __syncthreads();
            for (int i = t; i < 32 * 128; i += 256) {
                int kk = i >> 7, n = i & 127;
                Wl[kk * 129 + n] = W[(size_t)(k0 + kk) * 128 + n];
            }
            __syncthreads();
            int k = k0 + kl;
            float a  = bn[k] * rsqrtf(bn[3 * HIDD + k] + EPSS);
            float cc = bn[HIDD + k] - bn[2 * HIDD + k] * a;
            float ps = 0.f, pd = 0.f;
            #pragma unroll
            for (int c = 0; c < 16; ++c) {
                float wv = Wl[kl * 129 + h * 16 + c];
                ps += wv * as[h * 16 + c];
                pd += wv * ad[h * 16 + c];
            }
            Wo[(128 + h) * 128 + k] = f2bf(a * ps);
            Wo[(136 + h) * 128 + k] = f2bf(a * pd);
            acc_s += cc * ps;
            acc_d += cc * pd;
        }
        redS[t] = acc_s; redD[t] = acc_d;
        __syncthreads();
        if (t < 8) {
            float s = 0.f, d = 0.f;
            for (int q = 0; q < 32; ++q) { s += redS[q * 8 + t]; d += redD[q * 8 + t]; }
            bp[L * BSTRIDE + 128 + t] = s;
            bp[L * BSTRIDE + 136 + t] = d;
        }
    } else {
        unsigned int* stage = (unsigned int*)smem;        // 3125 entries (12500 B)
        int* hist = (int*)(smem + 12512);                 // 392 ints
        int* A    = hist + TABW;                          // 512 ints (scan)
        int k = blk - 23;
        int cbeg = k * BIN_CHUNK;
        int cend = cbeg + BIN_CHUNK;

        for (int i = t; i < TABW; i += 256) hist[i] = 0;
        __syncthreads();
        for (int e = cbeg + t; e < cend; e += 256)
            atomicAdd(&hist[dst[e] >> BSH], 1);
        __syncthreads();
        int i1 = t + 256;
        int c0 = hist[t];
        int c1 = (i1 < TABW) ? hist[i1] : 0;
        A[t] = c0; A[i1] = c1;
        __syncthreads();
        for (int d = 1; d < 512; d <<= 1) {
            int a0 = (t >= d) ? A[t - d] : 0;
            int a1 = A[i1 - d];
            __syncthreads();
            A[t] += a0; A[i1] += a1;
            __syncthreads();
        }
        int e0 = A[t] - c0;
        int e1 = A[i1] - c1;
        // transposed: tab[bucket * BIN_BLOCKS + chunk]
        tab[(size_t)t * BIN_BLOCKS + k] = e0;
        if (i1 < TABW) tab[(size_t)i1 * BIN_BLOCKS + k] = e1;
        hist[t] = e0;
        if (i1 < TABW) hist[i1] = e1;
        __syncthreads();
        for (int e = cbeg + t; e < cend; e += 256) {
            int d = dst[e];
            int b = d >> BSH;
            unsigned int pk = ((unsigned int)(d & (BSZ - 1)) << 16) | (unsigned int)src[e];
            int p = atomicAdd(&hist[b], 1);
            stage[p] = pk;
        }
        __syncthreads();
        for (int i = t; i < BIN_CHUNK; i += 256)
            tmp[(size_t)k * BIN_CHUNK + i] = stage[i];
    }
}

// ================================================================ kernel B: sort (391) + GEMM layer0 (391)  [R14-proven]
__global__ __launch_bounds__(256) void sort_gemm0(
    const int* __restrict__ tab, const unsigned int* __restrict__ tmp,
    ushort* __restrict__ csr, unsigned int* __restrict__ rowptr,
    const float* __restrict__ x, const ushort* __restrict__ Wt,
    const float* __restrict__ bp, ushort* __restrict__ h_a)
{
    int t = threadIdx.x;
    if (blockIdx.x < NB) {
        __shared__ unsigned int buf[SORT_BUF];   // 18432 B
        __shared__ int sc[256];
        __shared__ int o0s[256];
        __shared__ int hist[BSZ], pex[BSZ], cur[BSZ];
        int b = blockIdx.x;
        int base_out = b * CAPB;

        // transposed tab: coalesced column reads
        int o0 = tab[(size_t)b * BIN_BLOCKS + t];
        int o1 = tab[(size_t)(b + 1) * BIN_BLOCKS + t];
        int c = o1 - o0;
        o0s[t] = o0;
        sc[t] = c;
        __syncthreads();
        for (int d = 1; d < 256; d <<= 1) {
            int a = (t >= d) ? sc[t - d] : 0;
            __syncthreads();
            sc[t] += a;
            __syncthreads();
        }
        int m = sc[255];
        int mybase = sc[t] - c;
        if (m > CAPB - BSZ * 7) m = CAPB - BSZ * 7;
        for (int j = 0; j < c; ++j) {
            int p = mybase + j;
            if (p < m) buf[p] = tmp[(size_t)t * BIN_CHUNK + o0s[t] + j];
        }
        if (t < BSZ) hist[t] = 0;
        __syncthreads();
        for (int i = t; i < m; i += 256) atomicAdd(&hist[buf[i] >> 16], 1);
        __syncthreads();
        int pd = 0;
        if (t < BSZ) { pd = (hist[t] + 7) & ~7; pex[t] = pd; }
        __syncthreads();
        for (int d = 1; d < BSZ; d <<= 1) {
            int a = (t < BSZ && t >= d) ? pex[t - d] : 0;
            __syncthreads();
            if (t < BSZ) pex[t] += a;
            __syncthreads();
        }
        if (t < BSZ) {
            int ex = pex[t] - pd;
            pex[t] = ex;
            cur[t] = ex;
            int node = b * BSZ + t;
            if (node < NN)
                rowptr[node] = (unsigned int)(base_out + ex) | ((unsigned int)hist[t] << 21);
        }
        __syncthreads();
        for (int i = t; i < m; i += 256) {
            unsigned int pk = buf[i];
            int dl = pk >> 16;
            int p = atomicAdd(&cur[dl], 1);
            csr[base_out + p] = (ushort)(pk & 0xffffu);
        }
        __syncthreads();
        if (t < BSZ) {
            int ex = pex[t], hn = hist[t], pdn = (hn + 7) & ~7;
            for (int i = hn; i < pdn; ++i) csr[base_out + ex + i] = 0;
        }
    } else {
        gemm_core_l0(blockIdx.x - NB, t, x, Wt, bp, h_a, NN);
    }
}

// ================================================================ conv GEMM (layers 1-3): fp8 + alphas
__global__ __launch_bounds__(256) void gemm_conv(const ushort* __restrict__ Ain,
    const ushort* __restrict__ Wt, const float* __restrict__ bias,
    unsigned char* __restrict__ h8, float* __restrict__ alph_s,
    float* __restrict__ alph_d)
{
    __shared__ unsigned char tile[128 * TPITCH];   // ~16.9 KB
    int t = threadIdx.x;
    int wave = t >> 6, lane = t & 63;
    int m16 = lane & 15, quad = lane >> 4;
    int tile0 = blockIdx.x * 128;
    int rbase = tile0 + wave * 32;
    const int n = NN;

    short8 afrag[2][4];
    #pragma unroll
    for (int tt = 0; tt < 2; ++tt) {
        int arow_i = rbase + tt * 16 + m16;
        size_t arow = (size_t)(arow_i < n ? arow_i : 0) * HIDD + quad * 8;
        const ushort* ap = Ain + arow;
        #pragma unroll
        for (int kk = 0; kk < 4; ++kk)
            afrag[tt][kk] = *(const short8*)(ap + kk * 32);
    }

    f32x4 acc[2][9];
    #pragma unroll
    for (int tt = 0; tt < 2; ++tt)
        #pragma unroll
        for (int nt = 0; nt < 9; ++nt) acc[tt][nt] = (f32x4){0.f, 0.f, 0.f, 0.f};

    #pragma unroll
    for (int nt = 0; nt < 9; ++nt) {
        const ushort* brow = Wt + (size_t)(nt * 16 + m16) * HIDD + quad * 8;
        #pragma unroll
        for (int kk = 0; kk < 4; ++kk) {
            short8 bfrag = *(const short8*)(brow + kk * 32);
            acc[0][nt] = __builtin_amdgcn_mfma_f32_16x16x32_bf16(afrag[0][kk], bfrag, acc[0][nt], 0, 0, 0);
            acc[1][nt] = __builtin_amdgcn_mfma_f32_16x16x32_bf16(afrag[1][kk], bfrag, acc[1][nt], 0, 0, 0);
        }
    }

    #pragma unroll
    for (int tt = 0; tt < 2; ++tt) {
        int lrow = wave * 32 + tt * 16;
        #pragma unroll
        for (int nt = 0; nt < 8; ++nt) {
            int col = nt * 16 + m16;
            float bv = bias[col];
            #pragma unroll
            for (int r = 0; r < 4; ++r) {
                float v = acc[tt][nt][r] + bv;
                tile[(lrow + quad * 4 + r) * TPITCH + col] = f2fp8(v);
            }
        }
        {
            float bv = bias[128 + m16];
            int tb = rbase + tt * 16;
            #pragma unroll
            for (int r = 0; r < 4; ++r) {
                int orow = tb + quad * 4 + r;
                if (orow < n) {
                    float v = acc[tt][8][r] + bv;
                    if (m16 < 8) alph_s[orow * HEADS + m16] = v;
                    else         alph_d[orow * HEADS + (m16 - 8)] = v;
                }
            }
        }
    }
    __syncthreads();
    // coalesced dump: thread = (row = t>>1, half = t&1), 64 B each
    {
        int row = t >> 1, half = t & 1;
        int orow = tile0 + row;
        if (orow < n) {
            const unsigned char* srcp = &tile[row * TPITCH + half * 64];
            uint4* dstp = (uint4*)(h8 + (size_t)orow * HIDD + half * 64);
            #pragma unroll
            for (int j = 0; j < 4; ++j)
                dstp[j] = *(const uint4*)(srcp + j * 16);
        }
    }
}

// ================================================================ GAT aggregation v3 (R20)
// lane&7 = head (= one 16-ch block = 16B of the fp8 row), lane>>3 = edge slot.
// One dwordx4 gather per 8-edge group (vs 4 dword gathers), per-(edge,head)
// weight computed in-lane (no inner-loop shuffles). Epilogue: 8-lane-strided
// shfl_xor tree (8/16/32) reduces acc+denom; lanes 0..7 store 32B each.
__global__ __launch_bounds__(256) void gat_aggregate(
    const unsigned char* __restrict__ h8,
    const float* __restrict__ as, const float* __restrict__ ad,
    const unsigned int* __restrict__ rowptr, const ushort* __restrict__ csr,
    const float* __restrict__ bias, ushort* __restrict__ out)
{
    int wid = (blockIdx.x * 256 + threadIdx.x) >> 6;
    int v = __builtin_amdgcn_readfirstlane(wid);
    if (v >= NN) return;
    int lane = threadIdx.x & 63;
    int h = lane & 7;          // head == 16-channel block
    int slot = lane >> 3;      // edge slot within group of 8

    unsigned int rp = rowptr[v];
    int beg = rp & 0x1FFFFF;
    int cnt = rp >> 21;
    float adv = ad[v * HEADS + h];
    float wself = __expf(lrelu(as[v * HEADS + h] + adv));

    const uint4* h16 = (const uint4*)h8;   // 16 fp8 channels per uint4, 8/row

    float acc[16];
    {
        uint4 sx = h16[(size_t)v * 8 + h];
        float selfm = (slot == 0) ? wself : 0.f;   // count self once
        const unsigned int* sw = (const unsigned int*)&sx;
        #pragma unroll
        for (int q = 0; q < 4; ++q) {
            f32x2 lo = __builtin_amdgcn_cvt_pk_f32_fp8((int)sw[q], false);
            f32x2 hi = __builtin_amdgcn_cvt_pk_f32_fp8((int)sw[q], true);
            acc[4 * q + 0] = selfm * lo[0];
            acc[4 * q + 1] = selfm * lo[1];
            acc[4 * q + 2] = selfm * hi[0];
            acc[4 * q + 3] = selfm * hi[1];
        }
    }
    float wsum = 0.f;

    int ngro = (cnt + 7) >> 3;
    if (ngro > 0) {
        const uint4* epk = (const uint4*)(csr + beg);
        float l0, l1;
        uint4 x0, x1;
        {
            uint4 pk = epk[0];
            unsigned int d = slot < 4 ? (slot < 2 ? pk.x : pk.y)
                                      : (slot < 6 ? pk.z : pk.w);
            int u = (slot & 1) ? (int)(d >> 16) : (int)(d & 0xffff);
            l0 = as[u * HEADS + h];
            x0 = h16[(size_t)u * 8 + h];
        }
        for (int g = 0; g < ngro; ++g) {
            bool more = (g + 1 < ngro);
            if (more) {
                uint4 pk = epk[g + 1];
                unsigned int d = slot < 4 ? (slot < 2 ? pk.x : pk.y)
                                          : (slot < 6 ? pk.z : pk.w);
                int u = (slot & 1) ? (int)(d >> 16) : (int)(d & 0xffff);
                l1 = as[u * HEADS + h];
                x1 = h16[(size_t)u * 8 + h];
            }
            float w = __expf(lrelu(l0 + adv));
            if (g * 8 + slot >= cnt) w = 0.f;   // mask pad edges (point at node 0)
            wsum += w;
            const unsigned int* xw = (const unsigned int*)&x0;
            #pragma unroll
            for (int q = 0; q < 4; ++q) {
                f32x2 lo = __builtin_amdgcn_cvt_pk_f32_fp8((int)xw[q], false);
                f32x2 hi = __builtin_amdgcn_cvt_pk_f32_fp8((int)xw[q], true);
                acc[4 * q + 0] += w * lo[0];
                acc[4 * q + 1] += w * lo[1];
                acc[4 * q + 2] += w * hi[0];
                acc[4 * q + 3] += w * hi[1];
            }
            if (more) { l0 = l1; x0 = x1; }
        }
    }

    // reduce over the 8 edge slots (lane bits 3..5); head (bits 0..2) preserved
    #pragma unroll
    for (int off = 8; off < 64; off <<= 1) {
        wsum += __shfl_xor(wsum, off);
        #pragma unroll
        for (int i = 0; i < 16; ++i) acc[i] += __shfl_xor(acc[i], off);
    }
    float inv = 1.f / (wself + wsum + 1e-16f);

    if (slot == 0) {                 // lanes 0..7 write 16 channels each
        int c0 = h * 16;
        unsigned int wr[8];
        #pragma unroll
        for (int i = 0; i < 8; ++i) {
            float o0 = fmaxf(acc[2 * i]     * inv + bias[c0 + 2 * i],     0.f);
            float o1 = fmaxf(acc[2 * i + 1] * inv + bias[c0 + 2 * i + 1], 0.f);
            wr[i] = (unsigned int)f2bf(o0) | ((unsigned int)f2bf(o1) << 16);
        }
        uint4* orow = (uint4*)out + (size_t)v * 16 + h * 2;
        uint4 a; a.x = wr[0]; a.y = wr[1]; a.z = wr[2]; a.w = wr[3];
        uint4 b; b.x = wr[4]; b.y = wr[5]; b.z = wr[6]; b.w = wr[7];
        orow[0] = a;
        orow[1] = b;
    }
}

// ================================================================ pool + FC head (R16-proven, short8 loads)
__global__ __launch_bounds__(256) void pool_head(const ushort* __restrict__ h,
    const int* __restrict__ batch,
    const float* __restrict__ bns_fc, const float* __restrict__ fc_w,
    const float* __restrict__ fc_b, const float* __restrict__ bn_hid,
    const float* __restrict__ w_class, const float* __restrict__ b_class,
    float* __restrict__ out)
{
    __shared__ float sred[2048];     // 16 row-groups x 128 channels
    __shared__ float v1[HIDD];
    __shared__ float v2[HIDD];
    __shared__ float lg[NCLS];
    __shared__ float lse;
    __shared__ int bounds[2];
    int gb = blockIdx.x, t = threadIdx.x;

    if (t < 2) {
        int key = gb + t;
        int lo = 0, hi = NN;
        while (lo < hi) {
            int mid = (lo + hi) >> 1;
            if (batch[mid] < key) lo = mid + 1; else hi = mid;
        }
        bounds[t] = lo;
    }
    __syncthreads();
    int beg = bounds[0], end = bounds[1];

    int rg = t >> 4, cg = t & 15;    // row-group 0..15, col-group 0..15 (8 ch)
    float a[8] = {0.f, 0.f, 0.f, 0.f, 0.f, 0.f, 0.f, 0.f};
    for (int r = beg + rg; r < end; r += 16) {
        short8 vv = *(const short8*)(h + (size_t)r * HIDD + cg * 8);
        #pragma unroll
        for (int k = 0; k < 8; ++k) a[k] += bf2f((ushort)vv[k]);
    }
    #pragma unroll
    for (int k = 0; k < 8; ++k) sred[rg * 128 + cg * 8 + k] = a[k];
    __syncthreads();

    if (t < HIDD) {
        float gv = 0.f;
        #pragma unroll
        for (int q = 0; q < 16; ++q) gv += sred[q * 128 + t];
        float gamma = bns_fc[t], beta = bns_fc[HIDD + t];
        float mu = bns_fc[2 * HIDD + t], var = bns_fc[3 * HIDD + t];
        v1[t] = (gv - mu) * gamma * rsqrtf(var + EPSS) + beta;
    }
    __syncthreads();

    if (t < HIDD) {
        float acc = fc_b[t];
        for (int k = 0; k < HIDD; ++k) acc += v1[k] * fc_w[k * HIDD + t];
        acc = fmaxf(acc, 0.f);
        float gamma = bn_hid[t], beta = bn_hid[HIDD + t];
        float mu = bn_hid[2 * HIDD + t], var = bn_hid[3 * HIDD + t];
        v2[t] = (acc - mu) * gamma * rsqrtf(var + EPSS) + beta;
    }
    __syncthreads();

    if (t < NCLS) {
        float acc2 = b_class[t];
        for (int k = 0; k < HIDD; ++k) acc2 += v2[k] * w_class[k * NCLS + t];
        lg[t] = acc2;
    }
    __syncthreads();
    if (t == 0) {
        float mx = lg[0];
        for (int i = 1; i < NCLS; ++i) mx = fmaxf(mx, lg[i]);
        float ss = 0.f;
        for (int i = 0; i < NCLS; ++i) ss += __expf(lg[i] - mx);
        lse = mx + __logf(ss);
    }
    __syncthreads();
    if (t < NCLS) out[gb * NCLS + t] = lg[t] - lse;
}

// ================================================================ launch (9 dispatches)
extern "C" void kernel_launch(void* const* d_in, const int* in_sizes, int n_in,
                              void* d_out, int out_size, void* d_ws, size_t ws_size,
                              hipStream_t stream)
{
    const float* x        = (const float*)d_in[0];
    const int*   edge     = (const int*)d_in[1];
    const int*   batch    = (const int*)d_in[2];
    const float* bn_feat  = (const float*)d_in[3];
    const float* w_feat   = (const float*)d_in[4];
    const float* b_feat   = (const float*)d_in[5];
    const float* bns_conv = (const float*)d_in[6];
    const float* gat_w    = (const float*)d_in[7];
    const float* att_src  = (const float*)d_in[8];
    const float* att_dst  = (const float*)d_in[9];
    const float* gat_b    = (const float*)d_in[10];
    const float* bns_fc   = (const float*)d_in[11];
    const float* fc_w     = (const float*)d_in[12];
    const float* fc_b     = (const float*)d_in[13];
    const float* bn_hid   = (const float*)d_in[14];
    const float* w_class  = (const float*)d_in[15];
    const float* b_class  = (const float*)d_in[16];
    float* out = (float*)d_out;
    (void)in_sizes; (void)n_in; (void)out_size; (void)ws_size;

    char* ws = (char*)d_ws;
    size_t off = 0;
    auto alloc = [&](size_t bytes) {
        void* p = ws + off;
        off = (off + bytes + 255) & ~(size_t)255;
        return p;
    };
    ushort* Wt        = (ushort*)alloc((size_t)4 * WSTRIDE * sizeof(ushort));
    float*  bp        = (float*)alloc(4 * BSTRIDE * sizeof(float));
    ushort* h_a       = (ushort*)alloc((size_t)NN * HIDD * sizeof(ushort));
    unsigned char* h8 = (unsigned char*)alloc((size_t)NN * HIDD);
    float*  alph_s    = (float*)alloc((size_t)NN * HEADS * sizeof(float));
    float*  alph_d    = (float*)alloc((size_t)NN * HEADS * sizeof(float));
    int*    tab       = (int*)alloc((size_t)BIN_BLOCKS * TABW * sizeof(int));
    unsigned int* tmp = (unsigned int*)alloc((size_t)E_EDGES * sizeof(unsigned int));
    unsigned int* rowptr = (unsigned int*)alloc((size_t)NN * sizeof(unsigned int));
    ushort* csr       = (ushort*)alloc((size_t)NB * CAPB * sizeof(ushort) + 64);

    const int* src = edge;
    const int* dst = edge + E_EDGES;

    prep_bin<<<279, 256, 0, stream>>>(bn_feat, w_feat, b_feat, bns_conv, gat_w,
                                      att_src, att_dst, src, dst, Wt, bp, tmp, tab);
    sort_gemm0<<<NB + GTILES, 256, 0, stream>>>(tab, tmp, csr, rowptr,
                                                x, Wt, bp, h_a);

    for (int i = 0; i < NCONV; ++i) {
        gemm_conv<<<GTILES, 256, 0, stream>>>(h_a,
            Wt + (size_t)(i + 1) * WSTRIDE, bp + (i + 1) * BSTRIDE, h8,
            alph_s, alph_d);
        gat_aggregate<<<(NN + 3) / 4, 256, 0, stream>>>(h8, alph_s, alph_d,
                                                        rowptr, csr, gat_b + i * HIDD, h_a);
    }

    pool_head<<<NGG, 256, 0, stream>>>(h_a, batch, bns_fc, fc_w, fc_b, bn_hid,
                                       w_class, b_class, out);
}

// Round 7
// 291.081 us; speedup vs baseline: 1.0793x; 1.0793x over previous
//
#include <hip/hip_runtime.h>

#define NN 50000
#define E_EDGES 800000
#define F_INN 128
#define HIDD 128
#define HEADS 8
#define CDIM 16
#define NCLS 10
#define NGG 64
#define NCONV 3
#define EPSS 1e-5f
#define NEG_SLOPE 0.2f

// Wt layout: per layer 144 rows (output cols) x 128 k, bf16.
#define WROWS 144
#define WSTRIDE (WROWS * 128)
#define BSTRIDE 144

// bucket partition: 128 dst nodes per bucket
#define BSH 7
#define BSZ 128
#define NB ((NN + BSZ - 1) / BSZ)   // 391
#define BIN_BLOCKS 256
#define BIN_CHUNK (E_EDGES / BIN_BLOCKS)   // 3125 exact
#define TABW 392                     // 391 offsets + sentinel
#define CAPB 4608                    // fixed csr region/bucket
#define SORT_BUF 4608
#define PW_KCH 32
#define GTILES ((NN + 127) / 128)    // 391 gemm blocks (128 rows each)
#define TPITCH 132                   // fp8 LDS tile row pitch (pad 4)

typedef __attribute__((ext_vector_type(8))) short short8;
typedef __attribute__((ext_vector_type(4))) float f32x4;
typedef __attribute__((ext_vector_type(2))) float f32x2;

__device__ __forceinline__ float lrelu(float x) { return x > 0.f ? x : NEG_SLOPE * x; }

__device__ __forceinline__ float bf2f(ushort u) {
    union { unsigned int i; float f; } v;
    v.i = ((unsigned int)u) << 16;
    return v.f;
}
__device__ __forceinline__ ushort f2bf(float f) {
    union { float f; unsigned int i; } v;
    v.f = f;
    unsigned int r = (v.i + 0x7fffu + ((v.i >> 16) & 1u)) >> 16;  // RNE
    return (ushort)r;
}
// OCP e4m3 encode via HW pack (saturating); take byte 0
__device__ __forceinline__ unsigned char f2fp8(float f) {
    int r = __builtin_amdgcn_cvt_pk_fp8_f32(f, f, 0, false);
    return (unsigned char)(r & 0xff);
}

// ================================================================ GEMM core (bf16-out path, layer 0 only)
__device__ __forceinline__ void gemm_core_l0(int tile, int t,
    const float* __restrict__ Ain, const ushort* __restrict__ Wt,
    const float* __restrict__ bias, ushort* __restrict__ Out, int n)
{
    int wave = t >> 6, lane = t & 63;
    int m16 = lane & 15, quad = lane >> 4;
    int rbase = tile * 128 + wave * 32;

    short8 afrag[2][4];
    #pragma unroll
    for (int tt = 0; tt < 2; ++tt) {
        int arow_i = rbase + tt * 16 + m16;
        size_t arow = (size_t)(arow_i < n ? arow_i : 0) * HIDD + quad * 8;
        const float* ap = Ain + arow;
        #pragma unroll
        for (int kk = 0; kk < 4; ++kk) {
            float4 lo = *(const float4*)(ap + kk * 32);
            float4 hi = *(const float4*)(ap + kk * 32 + 4);
            short8 f;
            f[0] = (short)f2bf(lo.x); f[1] = (short)f2bf(lo.y);
            f[2] = (short)f2bf(lo.z); f[3] = (short)f2bf(lo.w);
            f[4] = (short)f2bf(hi.x); f[5] = (short)f2bf(hi.y);
            f[6] = (short)f2bf(hi.z); f[7] = (short)f2bf(hi.w);
            afrag[tt][kk] = f;
        }
    }

    f32x4 acc[2][8];
    #pragma unroll
    for (int tt = 0; tt < 2; ++tt)
        #pragma unroll
        for (int nt = 0; nt < 8; ++nt) acc[tt][nt] = (f32x4){0.f, 0.f, 0.f, 0.f};

    #pragma unroll
    for (int nt = 0; nt < 8; ++nt) {
        const ushort* brow = Wt + (size_t)(nt * 16 + m16) * HIDD + quad * 8;
        #pragma unroll
        for (int kk = 0; kk < 4; ++kk) {
            short8 bfrag = *(const short8*)(brow + kk * 32);
            acc[0][nt] = __builtin_amdgcn_mfma_f32_16x16x32_bf16(afrag[0][kk], bfrag, acc[0][nt], 0, 0, 0);
            acc[1][nt] = __builtin_amdgcn_mfma_f32_16x16x32_bf16(afrag[1][kk], bfrag, acc[1][nt], 0, 0, 0);
        }
    }

    #pragma unroll
    for (int tt = 0; tt < 2; ++tt) {
        int tb = rbase + tt * 16;
        #pragma unroll
        for (int nt = 0; nt < 8; ++nt) {
            int col = nt * 16 + m16;
            float bv = bias[col];
            #pragma unroll
            for (int r = 0; r < 4; ++r) {
                int orow = tb + quad * 4 + r;
                if (orow < n) {
                    float v = fmaxf(acc[tt][nt][r] + bv, 0.f);
                    Out[(size_t)orow * HIDD + col] = f2bf(v);
                }
            }
        }
    }
}

// ================================================================ kernel A: prep + bin (R14-proven)
// R16: tab transposed to [bucket][chunk] so sort blocks read it coalesced.
__global__ __launch_bounds__(256) void prep_bin(
    const float* __restrict__ bn_feat, const float* __restrict__ w_feat,
    const float* __restrict__ b_feat, const float* __restrict__ bns_conv,
    const float* __restrict__ gat_w, const float* __restrict__ att_src,
    const float* __restrict__ att_dst, const int* __restrict__ src,
    const int* __restrict__ dst, ushort* __restrict__ Wt,
    float* __restrict__ bp, unsigned int* __restrict__ tmp, int* __restrict__ tab)
{
    __shared__ __align__(16) char smem[18560];
    int blk = blockIdx.x;
    int t = threadIdx.x;

    if (blk < 16) {
        float* Wl = (float*)smem;            // 32*129 floats
        float* aak = Wl + PW_KCH * 129;
        int layer = blk >> 2;
        int k0 = (blk & 3) * PW_KCH;
        const float* bn; const float* W;
        if (layer == 0) { bn = bn_feat; W = w_feat; }
        else { bn = bns_conv + (layer - 1) * 4 * HIDD; W = gat_w + (size_t)(layer - 1) * HIDD * HIDD; }
        if (t < PW_KCH) {
            int k = k0 + t;
            aak[t] = bn[k] * rsqrtf(bn[3 * HIDD + k] + EPSS);
        }
        for (int i = t; i < PW_KCH * 128; i += 256) {
            int kk = i >> 7, n = i & 127;
            Wl[kk * 129 + n] = W[(size_t)(k0 + kk) * 128 + n];
        }
        __syncthreads();
        ushort* wrow = Wt + (size_t)layer * WSTRIDE;
        for (int i = t; i < 128 * PW_KCH; i += 256) {
            int n = i >> 5, kk = i & 31;
            wrow[n * 128 + k0 + kk] = f2bf(aak[kk] * Wl[kk * 129 + n]);
        }
    } else if (blk < 20) {
        float* ccs = (float*)smem;
        int layer = blk - 16;
        const float* bn; const float* W;
        if (layer == 0) { bn = bn_feat; W = w_feat; }
        else { bn = bns_conv + (layer - 1) * 4 * HIDD; W = gat_w + (size_t)(layer - 1) * HIDD * HIDD; }
        if (t < 128) {
            float a = bn[t] * rsqrtf(bn[3 * HIDD + t] + EPSS);
            ccs[t] = bn[HIDD + t] - bn[2 * HIDD + t] * a;
        }
        __syncthreads();
        if (t < 128) {
            float bacc = (layer == 0) ? b_feat[t] : 0.f;
            for (int k = 0; k < 128; ++k) bacc += ccs[k] * W[(size_t)k * 128 + t];
            bp[layer * BSTRIDE + t] = bacc;
        }
    } else if (blk < 23) {
        float* Wl   = (float*)smem;               // 32*129 floats (16512 B)
        float* redS = (float*)(smem + 16512);     // 256 floats
        float* redD = redS + 256;
        int li = blk - 20;
        int L = li + 1;
        const float* bn = bns_conv + li * 4 * HIDD;
        const float* W  = gat_w + (size_t)li * HIDD * HIDD;
        const float* as = att_src + li * HEADS * CDIM;
        const float* ad = att_dst + li * HEADS * CDIM;
        ushort* Wo = Wt + (size_t)L * WSTRIDE;
        int kl = t >> 3, h = t & 7;
        float acc_s = 0.f, acc_d = 0.f;
        for (int c0 = 0; c0 < 4; ++c0) {
            int k0 = c0 * 32;
            __syncthreads();
            for (int i = t; i < 32 * 128; i += 256) {
                int kk = i >> 7, n = i & 127;
                Wl[kk * 129 + n] = W[(size_t)(k0 + kk) * 128 + n];
            }
            __syncthreads();
            int k = k0 + kl;
            float a  = bn[k] * rsqrtf(bn[3 * HIDD + k] + EPSS);
            float cc = bn[HIDD + k] - bn[2 * HIDD + k] * a;
            float ps = 0.f, pd = 0.f;
            #pragma unroll
            for (int c = 0; c < 16; ++c) {
                float wv = Wl[kl * 129 + h * 16 + c];
                ps += wv * as[h * 16 + c];
                pd += wv * ad[h * 16 + c];
            }
            Wo[(128 + h) * 128 + k] = f2bf(a * ps);
            Wo[(136 + h) * 128 + k] = f2bf(a * pd);
            acc_s += cc * ps;
            acc_d += cc * pd;
        }
        redS[t] = acc_s; redD[t] = acc_d;
        __syncthreads();
        if (t < 8) {
            float s = 0.f, d = 0.f;
            for (int q = 0; q < 32; ++q) { s += redS[q * 8 + t]; d += redD[q * 8 + t]; }
            bp[L * BSTRIDE + 128 + t] = s;
            bp[L * BSTRIDE + 136 + t] = d;
        }
    } else {
        unsigned int* stage = (unsigned int*)smem;        // 3125 entries (12500 B)
        int* hist = (int*)(smem + 12512);                 // 392 ints
        int* A    = hist + TABW;                          // 512 ints (scan)
        int k = blk - 23;
        int cbeg = k * BIN_CHUNK;
        int cend = cbeg + BIN_CHUNK;

        for (int i = t; i < TABW; i += 256) hist[i] = 0;
        __syncthreads();
        for (int e = cbeg + t; e < cend; e += 256)
            atomicAdd(&hist[dst[e] >> BSH], 1);
        __syncthreads();
        int i1 = t + 256;
        int c0 = hist[t];
        int c1 = (i1 < TABW) ? hist[i1] : 0;
        A[t] = c0; A[i1] = c1;
        __syncthreads();
        for (int d = 1; d < 512; d <<= 1) {
            int a0 = (t >= d) ? A[t - d] : 0;
            int a1 = A[i1 - d];
            __syncthreads();
            A[t] += a0; A[i1] += a1;
            __syncthreads();
        }
        int e0 = A[t] - c0;
        int e1 = A[i1] - c1;
        // transposed: tab[bucket * BIN_BLOCKS + chunk]
        tab[(size_t)t * BIN_BLOCKS + k] = e0;
        if (i1 < TABW) tab[(size_t)i1 * BIN_BLOCKS + k] = e1;
        hist[t] = e0;
        if (i1 < TABW) hist[i1] = e1;
        __syncthreads();
        for (int e = cbeg + t; e < cend; e += 256) {
            int d = dst[e];
            int b = d >> BSH;
            unsigned int pk = ((unsigned int)(d & (BSZ - 1)) << 16) | (unsigned int)src[e];
            int p = atomicAdd(&hist[b], 1);
            stage[p] = pk;
        }
        __syncthreads();
        for (int i = t; i < BIN_CHUNK; i += 256)
            tmp[(size_t)k * BIN_CHUNK + i] = stage[i];
    }
}

// ================================================================ kernel B: sort (391) + GEMM layer0 (391)  [R14-proven]
__global__ __launch_bounds__(256) void sort_gemm0(
    const int* __restrict__ tab, const unsigned int* __restrict__ tmp,
    ushort* __restrict__ csr, unsigned int* __restrict__ rowptr,
    const float* __restrict__ x, const ushort* __restrict__ Wt,
    const float* __restrict__ bp, ushort* __restrict__ h_a)
{
    int t = threadIdx.x;
    if (blockIdx.x < NB) {
        __shared__ unsigned int buf[SORT_BUF];   // 18432 B
        __shared__ int sc[256];
        __shared__ int o0s[256];
        __shared__ int hist[BSZ], pex[BSZ], cur[BSZ];
        int b = blockIdx.x;
        int base_out = b * CAPB;

        // transposed tab: coalesced column reads
        int o0 = tab[(size_t)b * BIN_BLOCKS + t];
        int o1 = tab[(size_t)(b + 1) * BIN_BLOCKS + t];
        int c = o1 - o0;
        o0s[t] = o0;
        sc[t] = c;
        __syncthreads();
        for (int d = 1; d < 256; d <<= 1) {
            int a = (t >= d) ? sc[t - d] : 0;
            __syncthreads();
            sc[t] += a;
            __syncthreads();
        }
        int m = sc[255];
        int mybase = sc[t] - c;
        if (m > CAPB - BSZ * 7) m = CAPB - BSZ * 7;
        for (int j = 0; j < c; ++j) {
            int p = mybase + j;
            if (p < m) buf[p] = tmp[(size_t)t * BIN_CHUNK + o0s[t] + j];
        }
        if (t < BSZ) hist[t] = 0;
        __syncthreads();
        for (int i = t; i < m; i += 256) atomicAdd(&hist[buf[i] >> 16], 1);
        __syncthreads();
        int pd = 0;
        if (t < BSZ) { pd = (hist[t] + 7) & ~7; pex[t] = pd; }
        __syncthreads();
        for (int d = 1; d < BSZ; d <<= 1) {
            int a = (t < BSZ && t >= d) ? pex[t - d] : 0;
            __syncthreads();
            if (t < BSZ) pex[t] += a;
            __syncthreads();
        }
        if (t < BSZ) {
            int ex = pex[t] - pd;
            pex[t] = ex;
            cur[t] = ex;
            int node = b * BSZ + t;
            if (node < NN)
                rowptr[node] = (unsigned int)(base_out + ex) | ((unsigned int)hist[t] << 21);
        }
        __syncthreads();
        for (int i = t; i < m; i += 256) {
            unsigned int pk = buf[i];
            int dl = pk >> 16;
            int p = atomicAdd(&cur[dl], 1);
            csr[base_out + p] = (ushort)(pk & 0xffffu);
        }
        __syncthreads();
        if (t < BSZ) {
            int ex = pex[t], hn = hist[t], pdn = (hn + 7) & ~7;
            for (int i = hn; i < pdn; ++i) csr[base_out + ex + i] = 0;
        }
    } else {
        gemm_core_l0(blockIdx.x - NB, t, x, Wt, bp, h_a, NN);
    }
}

// ================================================================ conv GEMM (layers 1-3): fp8 + alphas
__global__ __launch_bounds__(256) void gemm_conv(const ushort* __restrict__ Ain,
    const ushort* __restrict__ Wt, const float* __restrict__ bias,
    unsigned char* __restrict__ h8, float* __restrict__ alph_s,
    float* __restrict__ alph_d)
{
    __shared__ unsigned char tile[128 * TPITCH];   // ~16.9 KB
    int t = threadIdx.x;
    int wave = t >> 6, lane = t & 63;
    int m16 = lane & 15, quad = lane >> 4;
    int tile0 = blockIdx.x * 128;
    int rbase = tile0 + wave * 32;
    const int n = NN;

    short8 afrag[2][4];
    #pragma unroll
    for (int tt = 0; tt < 2; ++tt) {
        int arow_i = rbase + tt * 16 + m16;
        size_t arow = (size_t)(arow_i < n ? arow_i : 0) * HIDD + quad * 8;
        const ushort* ap = Ain + arow;
        #pragma unroll
        for (int kk = 0; kk < 4; ++kk)
            afrag[tt][kk] = *(const short8*)(ap + kk * 32);
    }

    f32x4 acc[2][9];
    #pragma unroll
    for (int tt = 0; tt < 2; ++tt)
        #pragma unroll
        for (int nt = 0; nt < 9; ++nt) acc[tt][nt] = (f32x4){0.f, 0.f, 0.f, 0.f};

    #pragma unroll
    for (int nt = 0; nt < 9; ++nt) {
        const ushort* brow = Wt + (size_t)(nt * 16 + m16) * HIDD + quad * 8;
        #pragma unroll
        for (int kk = 0; kk < 4; ++kk) {
            short8 bfrag = *(const short8*)(brow + kk * 32);
            acc[0][nt] = __builtin_amdgcn_mfma_f32_16x16x32_bf16(afrag[0][kk], bfrag, acc[0][nt], 0, 0, 0);
            acc[1][nt] = __builtin_amdgcn_mfma_f32_16x16x32_bf16(afrag[1][kk], bfrag, acc[1][nt], 0, 0, 0);
        }
    }

    #pragma unroll
    for (int tt = 0; tt < 2; ++tt) {
        int lrow = wave * 32 + tt * 16;
        #pragma unroll
        for (int nt = 0; nt < 8; ++nt) {
            int col = nt * 16 + m16;
            float bv = bias[col];
            #pragma unroll
            for (int r = 0; r < 4; ++r) {
                float v = acc[tt][nt][r] + bv;
                tile[(lrow + quad * 4 + r) * TPITCH + col] = f2fp8(v);
            }
        }
        {
            float bv = bias[128 + m16];
            int tb = rbase + tt * 16;
            #pragma unroll
            for (int r = 0; r < 4; ++r) {
                int orow = tb + quad * 4 + r;
                if (orow < n) {
                    float v = acc[tt][8][r] + bv;
                    if (m16 < 8) alph_s[orow * HEADS + m16] = v;
                    else         alph_d[orow * HEADS + (m16 - 8)] = v;
                }
            }
        }
    }
    __syncthreads();
    // coalesced dump: thread = (row = t>>1, half = t&1), 64 B each
    {
        int row = t >> 1, half = t & 1;
        int orow = tile0 + row;
        if (orow < n) {
            const unsigned char* srcp = &tile[row * TPITCH + half * 64];
            uint4* dstp = (uint4*)(h8 + (size_t)orow * HIDD + half * 64);
            #pragma unroll
            for (int j = 0; j < 4; ++j)
                dstp[j] = *(const uint4*)(srcp + j * 16);
        }
    }
}

// ================================================================ GAT aggregation (R16-proven, 2 edges/gather)
__global__ __launch_bounds__(256) void gat_aggregate(
    const unsigned char* __restrict__ h8,
    const float* __restrict__ as, const float* __restrict__ ad,
    const unsigned int* __restrict__ rowptr, const ushort* __restrict__ csr,
    const float* __restrict__ bias, ushort* __restrict__ out)
{
    int wid = (blockIdx.x * 256 + threadIdx.x) >> 6;
    int v = __builtin_amdgcn_readfirstlane(wid);
    if (v >= NN) return;
    int lane = threadIdx.x & 63;
    int hd = lane >> 3;        // head, for weight lanes (edge slot x head grid)
    int slot = lane & 7;       // edge slot within group, for weight lanes
    int half = lane >> 5;      // 0: even edges, 1: odd edges
    int li = lane & 31;        // channel-group lane: owns channels 4li..4li+3
    int chh = li >> 2;         // head of owned channels

    unsigned int rp = rowptr[v];
    int beg = rp & 0x1FFFFF;
    int cnt = rp >> 21;
    float adv = ad[v * HEADS + hd];

    const unsigned int* h32 = (const unsigned int*)h8;   // 4 fp8 channels / uint

    // self edge
    float wself = __expf(lrelu(as[v * HEADS + hd] + adv));
    float wself_ch = __shfl(wself, chh * 8, 64);   // wself for owned channels' head
    unsigned int sx = h32[(size_t)v * 32 + li];
    f32x2 sl = __builtin_amdgcn_cvt_pk_f32_fp8((int)sx, false);
    f32x2 sh = __builtin_amdgcn_cvt_pk_f32_fp8((int)sx, true);
    float selfm = half ? 0.f : wself_ch;           // count self term once
    float acc0 = selfm * sl[0], acc1 = selfm * sl[1];
    float acc2 = selfm * sh[0], acc3 = selfm * sh[1];
    float wsum_own = 0.f;

    int ngro = (cnt + 7) >> 3;
    if (ngro > 0) {
        const uint4* epk = (const uint4*)(csr + beg);
        float l_own0, l_own1;
        int u0[4], u1[4];
        unsigned int x0[4], x1[4];
        {
            uint4 pk = epk[0];
            u0[0] = half ? (int)(pk.x >> 16) : (int)(pk.x & 0xffff);
            u0[1] = half ? (int)(pk.y >> 16) : (int)(pk.y & 0xffff);
            u0[2] = half ? (int)(pk.z >> 16) : (int)(pk.z & 0xffff);
            u0[3] = half ? (int)(pk.w >> 16) : (int)(pk.w & 0xffff);
            unsigned int d = slot < 4 ? (slot < 2 ? pk.x : pk.y)
                                      : (slot < 6 ? pk.z : pk.w);
            int u_own = (slot & 1) ? (int)(d >> 16) : (int)(d & 0xffff);
            l_own0 = as[u_own * HEADS + hd];
            #pragma unroll
            for (int j = 0; j < 4; ++j) x0[j] = h32[(size_t)u0[j] * 32 + li];
        }
        for (int g = 0; g < ngro; ++g) {
            bool more = (g + 1 < ngro);
            if (more) {
                uint4 pk = epk[g + 1];
                u1[0] = half ? (int)(pk.x >> 16) : (int)(pk.x & 0xffff);
                u1[1] = half ? (int)(pk.y >> 16) : (int)(pk.y & 0xffff);
                u1[2] = half ? (int)(pk.z >> 16) : (int)(pk.z & 0xffff);
                u1[3] = half ? (int)(pk.w >> 16) : (int)(pk.w & 0xffff);
                unsigned int d = slot < 4 ? (slot < 2 ? pk.x : pk.y)
                                          : (slot < 6 ? pk.z : pk.w);
                int u_own = (slot & 1) ? (int)(d >> 16) : (int)(d & 0xffff);
                l_own1 = as[u_own * HEADS + hd];
                #pragma unroll
                for (int j = 0; j < 4; ++j) x1[j] = h32[(size_t)u1[j] * 32 + li];
            }
            float w_own = __expf(lrelu(l_own0 + adv));
            if (g * 8 + slot >= cnt) w_own = 0.f;
            wsum_own += w_own;
            #pragma unroll
            for (int j = 0; j < 4; ++j) {
                // weight of edge (2j+half) for head chh lives at lane chh*8 + 2j+half
                float wj = __shfl(w_own, chh * 8 + 2 * j + half, 64);
                f32x2 lo = __builtin_amdgcn_cvt_pk_f32_fp8((int)x0[j], false);
                f32x2 hi = __builtin_amdgcn_cvt_pk_f32_fp8((int)x0[j], true);
                acc0 += wj * lo[0];
                acc1 += wj * lo[1];
                acc2 += wj * hi[0];
                acc3 += wj * hi[1];
            }
            if (more) {
                l_own0 = l_own1;
                #pragma unroll
                for (int j = 0; j < 4; ++j) { u0[j] = u1[j]; x0[j] = x1[j]; }
            }
        }
    }

    // per-head denom (softmax) — reduce over the 8 slots of each head group
    #pragma unroll
    for (int off = 1; off < 8; off <<= 1) wsum_own += __shfl_xor(wsum_own, off);
    float denom = wself + wsum_own;
    float inv_hd = 1.f / (denom + 1e-16f);
    float inv = __shfl(inv_hd, chh * 8, 64);

    // combine even-edge and odd-edge halves
    acc0 += __shfl_xor(acc0, 32);
    acc1 += __shfl_xor(acc1, 32);
    acc2 += __shfl_xor(acc2, 32);
    acc3 += __shfl_xor(acc3, 32);

    // half h writes channels 4li+2h, 4li+2h+1 (one dword of 2 bf16 per lane)
    float sa = half ? acc2 : acc0;
    float sb = half ? acc3 : acc1;
    int c0 = 4 * li + 2 * half;
    float o0 = fmaxf(sa * inv + bias[c0], 0.f);
    float o1 = fmaxf(sb * inv + bias[c0 + 1], 0.f);
    ((unsigned int*)out)[(size_t)v * 64 + 2 * li + half] =
        (unsigned int)f2bf(o0) | ((unsigned int)f2bf(o1) << 16);
}

// ================================================================ pool + FC head (R16-proven, short8 loads)
__global__ __launch_bounds__(256) void pool_head(const ushort* __restrict__ h,
    const int* __restrict__ batch,
    const float* __restrict__ bns_fc, const float* __restrict__ fc_w,
    const float* __restrict__ fc_b, const float* __restrict__ bn_hid,
    const float* __restrict__ w_class, const float* __restrict__ b_class,
    float* __restrict__ out)
{
    __shared__ float sred[2048];     // 16 row-groups x 128 channels
    __shared__ float v1[HIDD];
    __shared__ float v2[HIDD];
    __shared__ float lg[NCLS];
    __shared__ float lse;
    __shared__ int bounds[2];
    int gb = blockIdx.x, t = threadIdx.x;

    if (t < 2) {
        int key = gb + t;
        int lo = 0, hi = NN;
        while (lo < hi) {
            int mid = (lo + hi) >> 1;
            if (batch[mid] < key) lo = mid + 1; else hi = mid;
        }
        bounds[t] = lo;
    }
    __syncthreads();
    int beg = bounds[0], end = bounds[1];

    int rg = t >> 4, cg = t & 15;    // row-group 0..15, col-group 0..15 (8 ch)
    float a[8] = {0.f, 0.f, 0.f, 0.f, 0.f, 0.f, 0.f, 0.f};
    for (int r = beg + rg; r < end; r += 16) {
        short8 vv = *(const short8*)(h + (size_t)r * HIDD + cg * 8);
        #pragma unroll
        for (int k = 0; k < 8; ++k) a[k] += bf2f((ushort)vv[k]);
    }
    #pragma unroll
    for (int k = 0; k < 8; ++k) sred[rg * 128 + cg * 8 + k] = a[k];
    __syncthreads();

    if (t < HIDD) {
        float gv = 0.f;
        #pragma unroll
        for (int q = 0; q < 16; ++q) gv += sred[q * 128 + t];
        float gamma = bns_fc[t], beta = bns_fc[HIDD + t];
        float mu = bns_fc[2 * HIDD + t], var = bns_fc[3 * HIDD + t];
        v1[t] = (gv - mu) * gamma * rsqrtf(var + EPSS) + beta;
    }
    __syncthreads();

    if (t < HIDD) {
        float acc = fc_b[t];
        for (int k = 0; k < HIDD; ++k) acc += v1[k] * fc_w[k * HIDD + t];
        acc = fmaxf(acc, 0.f);
        float gamma = bn_hid[t], beta = bn_hid[HIDD + t];
        float mu = bn_hid[2 * HIDD + t], var = bn_hid[3 * HIDD + t];
        v2[t] = (acc - mu) * gamma * rsqrtf(var + EPSS) + beta;
    }
    __syncthreads();

    if (t < NCLS) {
        float acc2 = b_class[t];
        for (int k = 0; k < HIDD; ++k) acc2 += v2[k] * w_class[k * NCLS + t];
        lg[t] = acc2;
    }
    __syncthreads();
    if (t == 0) {
        float mx = lg[0];
        for (int i = 1; i < NCLS; ++i) mx = fmaxf(mx, lg[i]);
        float ss = 0.f;
        for (int i = 0; i < NCLS; ++i) ss += __expf(lg[i] - mx);
        lse = mx + __logf(ss);
    }
    __syncthreads();
    if (t < NCLS) out[gb * NCLS + t] = lg[t] - lse;
}

// ================================================================ launch (9 dispatches)
extern "C" void kernel_launch(void* const* d_in, const int* in_sizes, int n_in,
                              void* d_out, int out_size, void* d_ws, size_t ws_size,
                              hipStream_t stream)
{
    const float* x        = (const float*)d_in[0];
    const int*   edge     = (const int*)d_in[1];
    const int*   batch    = (const int*)d_in[2];
    const float* bn_feat  = (const float*)d_in[3];
    const float* w_feat   = (const float*)d_in[4];
    const float* b_feat   = (const float*)d_in[5];
    const float* bns_conv = (const float*)d_in[6];
    const float* gat_w    = (const float*)d_in[7];
    const float* att_src  = (const float*)d_in[8];
    const float* att_dst  = (const float*)d_in[9];
    const float* gat_b    = (const float*)d_in[10];
    const float* bns_fc   = (const float*)d_in[11];
    const float* fc_w     = (const float*)d_in[12];
    const float* fc_b     = (const float*)d_in[13];
    const float* bn_hid   = (const float*)d_in[14];
    const float* w_class  = (const float*)d_in[15];
    const float* b_class  = (const float*)d_in[16];
    float* out = (float*)d_out;
    (void)in_sizes; (void)n_in; (void)out_size; (void)ws_size;

    char* ws = (char*)d_ws;
    size_t off = 0;
    auto alloc = [&](size_t bytes) {
        void* p = ws + off;
        off = (off + bytes + 255) & ~(size_t)255;
        return p;
    };
    ushort* Wt        = (ushort*)alloc((size_t)4 * WSTRIDE * sizeof(ushort));
    float*  bp        = (float*)alloc(4 * BSTRIDE * sizeof(float));
    ushort* h_a       = (ushort*)alloc((size_t)NN * HIDD * sizeof(ushort));
    unsigned char* h8 = (unsigned char*)alloc((size_t)NN * HIDD);
    float*  alph_s    = (float*)alloc((size_t)NN * HEADS * sizeof(float));
    float*  alph_d    = (float*)alloc((size_t)NN * HEADS * sizeof(float));
    int*    tab       = (int*)alloc((size_t)BIN_BLOCKS * TABW * sizeof(int));
    unsigned int* tmp = (unsigned int*)alloc((size_t)E_EDGES * sizeof(unsigned int));
    unsigned int* rowptr = (unsigned int*)alloc((size_t)NN * sizeof(unsigned int));
    ushort* csr       = (ushort*)alloc((size_t)NB * CAPB * sizeof(ushort) + 64);

    const int* src = edge;
    const int* dst = edge + E_EDGES;

    prep_bin<<<279, 256, 0, stream>>>(bn_feat, w_feat, b_feat, bns_conv, gat_w,
                                      att_src, att_dst, src, dst, Wt, bp, tmp, tab);
    sort_gemm0<<<NB + GTILES, 256, 0, stream>>>(tab, tmp, csr, rowptr,
                                                x, Wt, bp, h_a);

    for (int i = 0; i < NCONV; ++i) {
        gemm_conv<<<GTILES, 256, 0, stream>>>(h_a,
            Wt + (size_t)(i + 1) * WSTRIDE, bp + (i + 1) * BSTRIDE, h8,
            alph_s, alph_d);
        gat_aggregate<<<(NN + 3) / 4, 256, 0, stream>>>(h8, alph_s, alph_d,
                                                        rowptr, csr, gat_b + i * HIDD, h_a);
    }

    pool_head<<<NGG, 256, 0, stream>>>(h_a, batch, bns_fc, fc_w, fc_b, bn_hid,
                                       w_class, b_class, out);
}